// Round 2
// baseline (205.546 us; speedup 1.0000x reference)
//
#include <hip/hip_runtime.h>

#define BB 16
#define CC 7
#define NN 32768
#define NCH (9*CC + 2*CC*CC)   // 161 output channels

__global__ __launch_bounds__(256) void feat_kernel(const float* __restrict__ x,
                                                   float* __restrict__ out) {
    const int t = blockIdx.x * blockDim.x + threadIdx.x;
    const int n0 = t << 2;              // this thread owns n0..n0+3
    const int b = blockIdx.y;

    const int m2 = (n0 >= 2) ? n0 - 2 : 0;
    const int m1 = (n0 >= 1) ? n0 - 1 : 0;
    const int p4 = (n0 + 4 < NN) ? n0 + 4 : NN - 1;
    const bool last = (n0 + 4 == NN);   // point k=3 is n = NN-1

    const float* xb = x + (size_t)b * (2 * CC) * NN * 2;
    float* ob = out + (size_t)b * NCH * NN + n0;

    float2 x1w[CC][5], x2w[CC][5];      // positions n0 .. n0+4 kept for pair loop

#pragma unroll
    for (int c = 0; c < CC; ++c) {
        const float* p1 = xb + (size_t)c * (NN * 2);
        const float* p2 = xb + (size_t)(c + CC) * (NN * 2);
        float2 w1[7], w2[7];            // positions n0-2 .. n0+4 (clamped)
        w1[0] = *(const float2*)(p1 + 2 * m2);
        w1[1] = *(const float2*)(p1 + 2 * m1);
        {
            float4 q0 = *(const float4*)(p1 + 2 * n0);
            float4 q1 = *(const float4*)(p1 + 2 * n0 + 4);
            w1[2] = make_float2(q0.x, q0.y); w1[3] = make_float2(q0.z, q0.w);
            w1[4] = make_float2(q1.x, q1.y); w1[5] = make_float2(q1.z, q1.w);
        }
        w1[6] = *(const float2*)(p1 + 2 * p4);
        w2[0] = *(const float2*)(p2 + 2 * m2);
        w2[1] = *(const float2*)(p2 + 2 * m1);
        {
            float4 q0 = *(const float4*)(p2 + 2 * n0);
            float4 q1 = *(const float4*)(p2 + 2 * n0 + 4);
            w2[2] = make_float2(q0.x, q0.y); w2[3] = make_float2(q0.z, q0.w);
            w2[4] = make_float2(q1.x, q1.y); w2[5] = make_float2(q1.z, q1.w);
        }
        w2[6] = *(const float2*)(p2 + 2 * p4);

        // dx at window positions 1..5 (dx[p] is the diff ending at position p)
        float dx1x[6], dx1y[6], dx2x[6], dx2y[6], nn1[6], nn2[6];
#pragma unroll
        for (int p = 1; p < 6; ++p) {
            dx1x[p] = w1[p].x - w1[p - 1].x; dx1y[p] = w1[p].y - w1[p - 1].y;
            dx2x[p] = w2[p].x - w2[p - 1].x; dx2y[p] = w2[p].y - w2[p - 1].y;
            nn1[p] = sqrtf(dx1x[p] * dx1x[p] + dx1y[p] * dx1y[p]);
            nn2[p] = sqrtf(dx2x[p] * dx2x[p] + dx2y[p] * dx2y[p]);
        }

        float o[9][4];
#pragma unroll
        for (int k = 0; k < 4; ++k) {
            const int pc = 2 + k;
            float dxx = dx1x[pc], dxy = dx1y[pc];
            float dpx = dx1x[pc - 1], dpy = dx1y[pc - 1];
            float exx = dx2x[pc], exy = dx2y[pc];
            float epx = dx2x[pc - 1], epy = dx2y[pc - 1];
            float n1 = nn1[pc], n1m = nn1[pc - 1];
            float n2 = nn2[pc], n2m = nn2[pc - 1];
            o[0][k] = n1;
            o[1][k] = n2;
            o[2][k] = dxx * (dxy - dpy) - dxy * (dxx - dpx);           // cross1
            o[3][k] = exx * (exy - epy) - exy * (exx - epx);           // cross2
            o[4][k] = (dxx * dpx + dxy * dpy) / (n1 * n1m + 1e-4f);    // adx1
            o[5][k] = (exx * epx + exy * epy) / (n2 * n2m + 1e-4f);    // adx2
            o[6][k] = (dxx * exx + dxy * exy) / (n1 * n2 + 1e-6f);     // dirs
            float rx = w1[pc].x - w2[pc].x, ry = w1[pc].y - w2[pc].y;
            float nr = sqrtf(rx * rx + ry * ry);
            o[7][k] = (dxx * rx + dxy * ry) / (n1 * nr + 1e-6f);       // lead1
            o[8][k] = -(exx * rx + exy * ry) / (n2 * nr + 1e-6f);      // lead2
        }

        *(float4*)(ob + (size_t)(0 * CC + c) * NN) = make_float4(o[0][0], o[0][1], o[0][2], o[0][3]);
        *(float4*)(ob + (size_t)(1 * CC + c) * NN) = make_float4(o[1][0], o[1][1], o[1][2], o[1][3]);
        *(float4*)(ob + (size_t)(2 * CC + c) * NN) = make_float4(o[2][0], o[2][1], o[2][2], o[2][3]);
        *(float4*)(ob + (size_t)(3 * CC + c) * NN) = make_float4(o[3][0], o[3][1], o[3][2], o[3][3]);
        *(float4*)(ob + (size_t)(4 * CC + c) * NN) = make_float4(o[4][0], o[4][1], o[4][2], o[4][3]);
        *(float4*)(ob + (size_t)(5 * CC + c) * NN) = make_float4(o[5][0], o[5][1], o[5][2], o[5][3]);
        *(float4*)(ob + (size_t)(6 * CC + c) * NN) = make_float4(o[6][0], o[6][1], o[6][2], o[6][3]);
        *(float4*)(ob + (size_t)(7 * CC + 2 * CC * CC + c) * NN)      = make_float4(o[7][0], o[7][1], o[7][2], o[7][3]);
        *(float4*)(ob + (size_t)(7 * CC + 2 * CC * CC + CC + c) * NN) = make_float4(o[8][0], o[8][1], o[8][2], o[8][3]);

#pragma unroll
        for (int p = 0; p < 5; ++p) { x1w[c][p] = w1[2 + p]; x2w[c][p] = w2[2 + p]; }
    }

#pragma unroll
    for (int i = 0; i < CC; ++i) {
#pragma unroll
        for (int j = 0; j < CC; ++j) {
            const int c1 = ((j - i - 1) % CC + CC) % CC;  // compile-time after unroll
            float d[5];
#pragma unroll
            for (int p = 0; p < 5; ++p) {
                float dx = x1w[c1][p].x - x2w[j][p].x + 1e-6f;
                float dy = x1w[c1][p].y - x2w[j][p].y + 1e-6f;
                d[p] = sqrtf(dx * dx + dy * dy);
            }
            float dd3 = last ? -d[3] : d[4] - d[3];
            *(float4*)(ob + (size_t)(7 * CC + i * CC + j) * NN) =
                make_float4(d[0], d[1], d[2], d[3]);
            *(float4*)(ob + (size_t)(7 * CC + CC * CC + i * CC + j) * NN) =
                make_float4(d[1] - d[0], d[2] - d[1], d[3] - d[2], dd3);
        }
    }
}

extern "C" void kernel_launch(void* const* d_in, const int* in_sizes, int n_in,
                              void* d_out, int out_size, void* d_ws, size_t ws_size,
                              hipStream_t stream) {
    const float* x = (const float*)d_in[0];
    float* out = (float*)d_out;
    dim3 grid(NN / 4 / 256, BB);
    feat_kernel<<<grid, 256, 0, stream>>>(x, out);
}

// Round 3
// 95.355 us; speedup vs baseline: 2.1556x; 2.1556x over previous
//
#include <hip/hip_runtime.h>

#define BB 16
#define CC 7
#define NN 32768
#define NCH 161   // [n1(7) n2(7) c1(7) c2(7) adx1(7) adx2(7) dirs(7) d(49) dd(49) l1(7) l2(7)]

__device__ __forceinline__ float2 ld2(const float* __restrict__ p, int n) {
    return *(const float2*)(p + 2 * n);
}

__global__ __launch_bounds__(256) void feat_kernel(const float* __restrict__ x,
                                                   float* __restrict__ out) {
    const int n0 = (blockIdx.x * 256 + threadIdx.x) << 2;   // 4 consecutive n
    const int vp = blockIdx.y;                              // virtual plane
    const int b  = blockIdx.z;

    const float* xb = x + (size_t)b * (2 * CC) * NN * 2;
    float* ob = out + (size_t)b * NCH * NN + n0;

    if (vp < 14) {
        // ---- per-trajectory features: n, cross, adx for channel c of set s ----
        const int s = vp / CC;                 // 0 -> x1, 1 -> x2
        const int c = vp % CC;
        const float* p = xb + (size_t)(c + s * CC) * NN * 2;
        float2 w[6];                           // positions n0-2 .. n0+3 (clamped)
        w[0] = ld2(p, n0 >= 2 ? n0 - 2 : 0);
        w[1] = ld2(p, n0 >= 1 ? n0 - 1 : 0);
        float4 q0 = *(const float4*)(p + 2 * n0);
        float4 q1 = *(const float4*)(p + 2 * n0 + 4);
        w[2] = make_float2(q0.x, q0.y); w[3] = make_float2(q0.z, q0.w);
        w[4] = make_float2(q1.x, q1.y); w[5] = make_float2(q1.z, q1.w);

        float dx[5], dy[5], nr[5];
#pragma unroll
        for (int m = 0; m < 5; ++m) {
            dx[m] = w[m + 1].x - w[m].x;
            dy[m] = w[m + 1].y - w[m].y;
            nr[m] = sqrtf(dx[m] * dx[m] + dy[m] * dy[m]);
        }
        float4 on, oc, oa;
        float* vn = &on.x; float* vc = &oc.x; float* va = &oa.x;
#pragma unroll
        for (int k = 0; k < 4; ++k) {
            vn[k] = nr[k + 1];
            vc[k] = dx[k + 1] * (dy[k + 1] - dy[k]) - dy[k + 1] * (dx[k + 1] - dx[k]);
            va[k] = (dx[k + 1] * dx[k] + dy[k + 1] * dy[k]) / (nr[k + 1] * nr[k] + 1e-4f);
        }
        *(float4*)(ob + (size_t)(s * CC + c) * NN)       = on;
        *(float4*)(ob + (size_t)((2 + s) * CC + c) * NN) = oc;
        *(float4*)(ob + (size_t)((4 + s) * CC + c) * NN) = oa;
    } else if (vp < 21) {
        // ---- dirs / lead1 / lead2 for channel c ----
        const int c = vp - 14;
        const float* p1 = xb + (size_t)c * NN * 2;
        const float* p2 = xb + (size_t)(c + CC) * NN * 2;
        float2 w1[5], w2[5];                   // positions n0-1 .. n0+3
        w1[0] = ld2(p1, n0 >= 1 ? n0 - 1 : 0);
        w2[0] = ld2(p2, n0 >= 1 ? n0 - 1 : 0);
        float4 a0 = *(const float4*)(p1 + 2 * n0);
        float4 a1 = *(const float4*)(p1 + 2 * n0 + 4);
        float4 b0 = *(const float4*)(p2 + 2 * n0);
        float4 b1 = *(const float4*)(p2 + 2 * n0 + 4);
        w1[1] = make_float2(a0.x, a0.y); w1[2] = make_float2(a0.z, a0.w);
        w1[3] = make_float2(a1.x, a1.y); w1[4] = make_float2(a1.z, a1.w);
        w2[1] = make_float2(b0.x, b0.y); w2[2] = make_float2(b0.z, b0.w);
        w2[3] = make_float2(b1.x, b1.y); w2[4] = make_float2(b1.z, b1.w);

        float4 od, ol1, ol2;
        float* vd = &od.x; float* v1 = &ol1.x; float* v2 = &ol2.x;
#pragma unroll
        for (int k = 0; k < 4; ++k) {
            float d1x = w1[k + 1].x - w1[k].x, d1y = w1[k + 1].y - w1[k].y;
            float d2x = w2[k + 1].x - w2[k].x, d2y = w2[k + 1].y - w2[k].y;
            float n1 = sqrtf(d1x * d1x + d1y * d1y);
            float n2 = sqrtf(d2x * d2x + d2y * d2y);
            float rx = w1[k + 1].x - w2[k + 1].x, ry = w1[k + 1].y - w2[k + 1].y;
            float nr = sqrtf(rx * rx + ry * ry);
            vd[k] = (d1x * d2x + d1y * d2y) / (n1 * n2 + 1e-6f);
            v1[k] = (d1x * rx + d1y * ry) / (n1 * nr + 1e-6f);
            v2[k] = -(d2x * rx + d2y * ry) / (n2 * nr + 1e-6f);
        }
        *(float4*)(ob + (size_t)(6 * CC + c) * NN)                    = od;
        *(float4*)(ob + (size_t)(7 * CC + 2 * CC * CC + c) * NN)      = ol1;
        *(float4*)(ob + (size_t)(7 * CC + 2 * CC * CC + CC + c) * NN) = ol2;
    } else {
        // ---- pair distance d and dd for pair (i,j) ----
        const int pair = vp - 21;
        const int i = pair / CC;
        const int j = pair - i * CC;
        const int c1 = ((j - i - 1) % CC + CC) % CC;
        const float* p1 = xb + (size_t)c1 * NN * 2;
        const float* p2 = xb + (size_t)j * NN * 2 + (size_t)CC * NN * 2;
        float4 a0 = *(const float4*)(p1 + 2 * n0);
        float4 a1 = *(const float4*)(p1 + 2 * n0 + 4);
        float4 b0 = *(const float4*)(p2 + 2 * n0);
        float4 b1 = *(const float4*)(p2 + 2 * n0 + 4);
        const int p4 = (n0 + 4 < NN) ? n0 + 4 : NN - 1;
        float2 a2 = ld2(p1, p4), b2 = ld2(p2, p4);

        float w1x[5] = {a0.x, a0.z, a1.x, a1.z, a2.x};
        float w1y[5] = {a0.y, a0.w, a1.y, a1.w, a2.y};
        float w2x[5] = {b0.x, b0.z, b1.x, b1.z, b2.x};
        float w2y[5] = {b0.y, b0.w, b1.y, b1.w, b2.y};
        float d[5];
#pragma unroll
        for (int p = 0; p < 5; ++p) {
            float ddx = w1x[p] - w2x[p] + 1e-6f;
            float ddy = w1y[p] - w2y[p] + 1e-6f;
            d[p] = sqrtf(ddx * ddx + ddy * ddy);
        }
        const bool last = (n0 + 4 == NN);
        float dd3 = last ? -d[3] : d[4] - d[3];
        *(float4*)(ob + (size_t)(7 * CC + i * CC + j) * NN) =
            make_float4(d[0], d[1], d[2], d[3]);
        *(float4*)(ob + (size_t)(7 * CC + CC * CC + i * CC + j) * NN) =
            make_float4(d[1] - d[0], d[2] - d[1], d[3] - d[2], dd3);
    }
}

extern "C" void kernel_launch(void* const* d_in, const int* in_sizes, int n_in,
                              void* d_out, int out_size, void* d_ws, size_t ws_size,
                              hipStream_t stream) {
    const float* x = (const float*)d_in[0];
    float* out = (float*)d_out;
    dim3 grid(NN / 4 / 256, 70, BB);
    feat_kernel<<<grid, 256, 0, stream>>>(x, out);
}

// Round 4
// 87.927 us; speedup vs baseline: 2.3377x; 1.0845x over previous
//
#include <hip/hip_runtime.h>

#define CC 7
#define NN 32768
#define NCH 161
#define SPAN 256          // n per workgroup
#define W    264          // staged float2 per channel: window [N0-2, N0+261], padded
// plane layout: n1 0-6 | n2 7-13 | cross1 14-20 | cross2 21-27 | adx1 28-34 |
//               adx2 35-41 | dirs 42-48 | d 49-97 | dd 98-146 | lead1 147-153 | lead2 154-160

__global__ __launch_bounds__(256) void feat_kernel(const float* __restrict__ x,
                                                   float* __restrict__ out) {
    __shared__ float2 S[2 * CC][W];
    const int t  = threadIdx.x;
    const int N0 = blockIdx.x * SPAN;
    const int b  = blockIdx.y;

    const float* xb = x + (size_t)b * (2 * CC) * NN * 2;

    // ---- stage 14 channels x W float2 into LDS (float4 = 2 float2 at a time) ----
    for (int idx = t; idx < 2 * CC * (W / 2); idx += 256) {
        int ch = idx / (W / 2);
        int m  = idx - ch * (W / 2);
        int g0 = N0 - 2 + 2 * m;                      // global pos of first float2
        const float* p = xb + (size_t)ch * NN * 2;
        float4 v;
        if (g0 >= 0 && g0 + 1 < NN) {
            v = *(const float4*)(p + 2 * g0);
        } else {
            int ga = g0     < 0 ? 0 : (g0     > NN - 1 ? NN - 1 : g0);
            int gb = g0 + 1 < 0 ? 0 : (g0 + 1 > NN - 1 ? NN - 1 : g0 + 1);
            float2 va = *(const float2*)(p + 2 * ga);
            float2 vb = *(const float2*)(p + 2 * gb);
            v = make_float4(va.x, va.y, vb.x, vb.y);
        }
        *(float4*)&S[ch][2 * m] = v;
    }
    __syncthreads();

    const int wg = t >> 6;           // wave-group 0..3 (plane selector)
    const int tl = t & 63;           // lane: owns n = N0+4tl .. N0+4tl+3
    const int p0 = 4 * tl;           // pos2 of (n-2);  n <-> pos2 4tl+2
    float* ob = out + (size_t)b * NCH * NN + N0 + 4 * tl;

    // ---- phase 1: n / cross / adx for 14 channels ----
#pragma unroll
    for (int it = 0; it < 4; ++it) {
        const int ch = it * 4 + wg;
        if (ch < 14) {
            float4 A = *(const float4*)&S[ch][p0];
            float4 Bq = *(const float4*)&S[ch][p0 + 2];
            float4 Cq = *(const float4*)&S[ch][p0 + 4];
            float wx[6] = {A.x, A.z, Bq.x, Bq.z, Cq.x, Cq.z};
            float wy[6] = {A.y, A.w, Bq.y, Bq.w, Cq.y, Cq.w};
            float dx[5], dy[5], nr[5];
#pragma unroll
            for (int m = 0; m < 5; ++m) {
                dx[m] = wx[m + 1] - wx[m];
                dy[m] = wy[m + 1] - wy[m];
                nr[m] = sqrtf(dx[m] * dx[m] + dy[m] * dy[m]);
            }
            float4 on, oc, oa;
            float* vn = &on.x; float* vc = &oc.x; float* va = &oa.x;
#pragma unroll
            for (int k = 0; k < 4; ++k) {
                vn[k] = nr[k + 1];
                vc[k] = dx[k + 1] * (dy[k + 1] - dy[k]) - dy[k + 1] * (dx[k + 1] - dx[k]);
                va[k] = (dx[k + 1] * dx[k] + dy[k + 1] * dy[k]) / (nr[k + 1] * nr[k] + 1e-4f);
            }
            *(float4*)(ob + (size_t)(ch) * NN)      = on;
            *(float4*)(ob + (size_t)(14 + ch) * NN) = oc;
            *(float4*)(ob + (size_t)(28 + ch) * NN) = oa;
        }
    }

    // ---- phase 2: dirs / lead1 / lead2 for 7 channel-pairs ----
#pragma unroll
    for (int it = 0; it < 2; ++it) {
        const int c = it * 4 + wg;
        if (c < 7) {
            float2 a0 = S[c][p0 + 1];
            float4 A1 = *(const float4*)&S[c][p0 + 2];
            float4 A2 = *(const float4*)&S[c][p0 + 4];
            float2 b0 = S[c + CC][p0 + 1];
            float4 B1 = *(const float4*)&S[c + CC][p0 + 2];
            float4 B2 = *(const float4*)&S[c + CC][p0 + 4];
            float w1x[5] = {a0.x, A1.x, A1.z, A2.x, A2.z};
            float w1y[5] = {a0.y, A1.y, A1.w, A2.y, A2.w};
            float w2x[5] = {b0.x, B1.x, B1.z, B2.x, B2.z};
            float w2y[5] = {b0.y, B1.y, B1.w, B2.y, B2.w};
            float4 od, ol1, ol2;
            float* vd = &od.x; float* v1 = &ol1.x; float* v2 = &ol2.x;
#pragma unroll
            for (int k = 0; k < 4; ++k) {
                float d1x = w1x[k + 1] - w1x[k], d1y = w1y[k + 1] - w1y[k];
                float d2x = w2x[k + 1] - w2x[k], d2y = w2y[k + 1] - w2y[k];
                float n1 = sqrtf(d1x * d1x + d1y * d1y);
                float n2 = sqrtf(d2x * d2x + d2y * d2y);
                float rx = w1x[k + 1] - w2x[k + 1], ry = w1y[k + 1] - w2y[k + 1];
                float nr = sqrtf(rx * rx + ry * ry);
                vd[k] = (d1x * d2x + d1y * d2y) / (n1 * n2 + 1e-6f);
                v1[k] = (d1x * rx + d1y * ry) / (n1 * nr + 1e-6f);
                v2[k] = -(d2x * rx + d2y * ry) / (n2 * nr + 1e-6f);
            }
            *(float4*)(ob + (size_t)(42 + c) * NN)  = od;
            *(float4*)(ob + (size_t)(147 + c) * NN) = ol1;
            *(float4*)(ob + (size_t)(154 + c) * NN) = ol2;
        }
    }

    // ---- phase 3: d / dd for 49 pairs ----
    const bool lastpt = (N0 + 4 * tl + 4 == NN);
#pragma unroll
    for (int it = 0; it < 13; ++it) {
        const int pair = it * 4 + wg;
        if (pair < 49) {
            const int i = pair / 7;
            const int j = pair - i * 7;
            const int c1 = ((j - i - 1) % 7 + 7) % 7;
            float4 A1 = *(const float4*)&S[c1][p0 + 2];
            float4 A2 = *(const float4*)&S[c1][p0 + 4];
            float2 a2 = S[c1][p0 + 6];
            float4 B1 = *(const float4*)&S[CC + j][p0 + 2];
            float4 B2 = *(const float4*)&S[CC + j][p0 + 4];
            float2 b2 = S[CC + j][p0 + 6];
            float w1x[5] = {A1.x, A1.z, A2.x, A2.z, a2.x};
            float w1y[5] = {A1.y, A1.w, A2.y, A2.w, a2.y};
            float w2x[5] = {B1.x, B1.z, B2.x, B2.z, b2.x};
            float w2y[5] = {B1.y, B1.w, B2.y, B2.w, b2.y};
            float d[5];
#pragma unroll
            for (int p = 0; p < 5; ++p) {
                float ddx = w1x[p] - w2x[p] + 1e-6f;
                float ddy = w1y[p] - w2y[p] + 1e-6f;
                d[p] = sqrtf(ddx * ddx + ddy * ddy);
            }
            float dd3 = lastpt ? -d[3] : d[4] - d[3];
            *(float4*)(ob + (size_t)(49 + pair) * NN) =
                make_float4(d[0], d[1], d[2], d[3]);
            *(float4*)(ob + (size_t)(98 + pair) * NN) =
                make_float4(d[1] - d[0], d[2] - d[1], d[3] - d[2], dd3);
        }
    }
}

extern "C" void kernel_launch(void* const* d_in, const int* in_sizes, int n_in,
                              void* d_out, int out_size, void* d_ws, size_t ws_size,
                              hipStream_t stream) {
    const float* x = (const float*)d_in[0];
    float* out = (float*)d_out;
    dim3 grid(NN / SPAN, 16);
    feat_kernel<<<grid, 256, 0, stream>>>(x, out);
}

// Round 6
// 69.749 us; speedup vs baseline: 2.9469x; 1.2606x over previous
//
#include <hip/hip_runtime.h>

#define CC 7
#define NN 32768
#define NCH 161
#define SPAN 256          // n per workgroup
#define W    264          // floats per coord row: pos2 window [N0-2 .. N0+261]
// pos p in row  <->  n = N0 - 2 + p.  Lane tl owns n = N0+4tl .. N0+4tl+3 (p0 = 4tl).
// plane layout: n1 0-6 | n2 7-13 | cross1 14-20 | cross2 21-27 | adx1 28-34 |
//               adx2 35-41 | dirs 42-48 | d 49-97 | dd 98-146 | lead1 147-153 | lead2 154-160

typedef float vfloat4 __attribute__((ext_vector_type(4)));

__device__ __forceinline__ void stnt4(float* p, float4 v) {
    vfloat4 w = {v.x, v.y, v.z, v.w};
    __builtin_nontemporal_store(w, (vfloat4*)p);
}

__global__ __launch_bounds__(256) void feat_kernel(const float* __restrict__ x,
                                                   float* __restrict__ out) {
    __shared__ float S[2 * CC][2][W];          // [channel][coord x/y][pos]
    const int t  = threadIdx.x;
    const int N0 = blockIdx.x * SPAN;
    const int b  = blockIdx.y;

    const float* xb = x + (size_t)b * (2 * CC) * NN * 2;

    // ---- stage: global float2 AoS -> LDS SoA (x-row, y-row per channel) ----
    for (int idx = t; idx < 2 * CC * (W / 2); idx += 256) {
        int ch = idx / (W / 2);
        int m  = idx - ch * (W / 2);
        int g0 = N0 - 2 + 2 * m;               // global n of first of 2 points
        const float* p = xb + (size_t)ch * NN * 2;
        float4 v;
        if (g0 >= 0 && g0 + 1 < NN) {
            v = *(const float4*)(p + 2 * g0);
        } else {
            int ga = g0     < 0 ? 0 : (g0     > NN - 1 ? NN - 1 : g0);
            int gb = g0 + 1 < 0 ? 0 : (g0 + 1 > NN - 1 ? NN - 1 : g0 + 1);
            float2 va = *(const float2*)(p + 2 * ga);
            float2 vb = *(const float2*)(p + 2 * gb);
            v = make_float4(va.x, va.y, vb.x, vb.y);
        }
        *(float2*)&S[ch][0][2 * m] = make_float2(v.x, v.z);
        *(float2*)&S[ch][1][2 * m] = make_float2(v.y, v.w);
    }
    __syncthreads();

    const int wg = t >> 6;                     // wave-group 0..3
    const int tl = t & 63;
    const int p0 = 4 * tl;
    float* ob = out + (size_t)b * NCH * NN + N0 + 4 * tl;

    // ---- phase 1: n / cross / adx for 14 channels ----
#pragma unroll
    for (int it = 0; it < 4; ++it) {
        const int ch = it * 4 + wg;
        if (ch < 14) {
            float4 X0 = *(const float4*)&S[ch][0][p0];
            float4 X1 = *(const float4*)&S[ch][0][p0 + 4];
            float4 Y0 = *(const float4*)&S[ch][1][p0];
            float4 Y1 = *(const float4*)&S[ch][1][p0 + 4];
            float wx[6] = {X0.x, X0.y, X0.z, X0.w, X1.x, X1.y};
            float wy[6] = {Y0.x, Y0.y, Y0.z, Y0.w, Y1.x, Y1.y};
            float dx[5], dy[5], nr[5];
#pragma unroll
            for (int m = 0; m < 5; ++m) {
                dx[m] = wx[m + 1] - wx[m];
                dy[m] = wy[m + 1] - wy[m];
                nr[m] = sqrtf(dx[m] * dx[m] + dy[m] * dy[m]);
            }
            float4 on, oc, oa;
            float* vn = &on.x; float* vc = &oc.x; float* va = &oa.x;
#pragma unroll
            for (int k = 0; k < 4; ++k) {
                vn[k] = nr[k + 1];
                vc[k] = dx[k + 1] * (dy[k + 1] - dy[k]) - dy[k + 1] * (dx[k + 1] - dx[k]);
                va[k] = (dx[k + 1] * dx[k] + dy[k + 1] * dy[k]) / (nr[k + 1] * nr[k] + 1e-4f);
            }
            stnt4(ob + (size_t)(ch) * NN,      on);
            stnt4(ob + (size_t)(14 + ch) * NN, oc);
            stnt4(ob + (size_t)(28 + ch) * NN, oa);
        }
    }

    // ---- phase 2: dirs / lead1 / lead2 ----
#pragma unroll
    for (int it = 0; it < 2; ++it) {
        const int c = it * 4 + wg;
        if (c < 7) {
            float4 AX0 = *(const float4*)&S[c][0][p0];
            float4 AX1 = *(const float4*)&S[c][0][p0 + 4];
            float4 AY0 = *(const float4*)&S[c][1][p0];
            float4 AY1 = *(const float4*)&S[c][1][p0 + 4];
            float4 BX0 = *(const float4*)&S[c + CC][0][p0];
            float4 BX1 = *(const float4*)&S[c + CC][0][p0 + 4];
            float4 BY0 = *(const float4*)&S[c + CC][1][p0];
            float4 BY1 = *(const float4*)&S[c + CC][1][p0 + 4];
            float w1x[5] = {AX0.y, AX0.z, AX0.w, AX1.x, AX1.y};
            float w1y[5] = {AY0.y, AY0.z, AY0.w, AY1.x, AY1.y};
            float w2x[5] = {BX0.y, BX0.z, BX0.w, BX1.x, BX1.y};
            float w2y[5] = {BY0.y, BY0.z, BY0.w, BY1.x, BY1.y};
            float4 od, ol1, ol2;
            float* vd = &od.x; float* v1 = &ol1.x; float* v2 = &ol2.x;
#pragma unroll
            for (int k = 0; k < 4; ++k) {
                float d1x = w1x[k + 1] - w1x[k], d1y = w1y[k + 1] - w1y[k];
                float d2x = w2x[k + 1] - w2x[k], d2y = w2y[k + 1] - w2y[k];
                float n1 = sqrtf(d1x * d1x + d1y * d1y);
                float n2 = sqrtf(d2x * d2x + d2y * d2y);
                float rx = w1x[k + 1] - w2x[k + 1], ry = w1y[k + 1] - w2y[k + 1];
                float nr = sqrtf(rx * rx + ry * ry);
                vd[k] = (d1x * d2x + d1y * d2y) / (n1 * n2 + 1e-6f);
                v1[k] = (d1x * rx + d1y * ry) / (n1 * nr + 1e-6f);
                v2[k] = -(d2x * rx + d2y * ry) / (n2 * nr + 1e-6f);
            }
            stnt4(ob + (size_t)(42 + c) * NN,  od);
            stnt4(ob + (size_t)(147 + c) * NN, ol1);
            stnt4(ob + (size_t)(154 + c) * NN, ol2);
        }
    }

    // ---- phase 3: d / dd, j-column blocked per wave-group ----
    const bool lastpt = (N0 + 4 * tl + 4 == NN);
    for (int j = wg; j < 7; j += 4) {
        float4 BX0 = *(const float4*)&S[CC + j][0][p0];
        float4 BX1 = *(const float4*)&S[CC + j][0][p0 + 4];
        float4 BY0 = *(const float4*)&S[CC + j][1][p0];
        float4 BY1 = *(const float4*)&S[CC + j][1][p0 + 4];
        float w2x[5] = {BX0.z, BX0.w, BX1.x, BX1.y, BX1.z};
        float w2y[5] = {BY0.z, BY0.w, BY1.x, BY1.y, BY1.z};
#pragma unroll
        for (int i = 0; i < 7; ++i) {
            int c1 = j - i - 1;
            c1 = (c1 < 0) ? c1 + 7 : c1;
            float4 AX0 = *(const float4*)&S[c1][0][p0];
            float4 AX1 = *(const float4*)&S[c1][0][p0 + 4];
            float4 AY0 = *(const float4*)&S[c1][1][p0];
            float4 AY1 = *(const float4*)&S[c1][1][p0 + 4];
            float w1x[5] = {AX0.z, AX0.w, AX1.x, AX1.y, AX1.z};
            float w1y[5] = {AY0.z, AY0.w, AY1.x, AY1.y, AY1.z};
            float d[5];
#pragma unroll
            for (int p = 0; p < 5; ++p) {
                float ddx = w1x[p] - w2x[p] + 1e-6f;
                float ddy = w1y[p] - w2y[p] + 1e-6f;
                d[p] = sqrtf(ddx * ddx + ddy * ddy);
            }
            float dd3 = lastpt ? -d[3] : d[4] - d[3];
            const int pair = i * 7 + j;
            stnt4(ob + (size_t)(49 + pair) * NN,
                  make_float4(d[0], d[1], d[2], d[3]));
            stnt4(ob + (size_t)(98 + pair) * NN,
                  make_float4(d[1] - d[0], d[2] - d[1], d[3] - d[2], dd3));
        }
    }
}

extern "C" void kernel_launch(void* const* d_in, const int* in_sizes, int n_in,
                              void* d_out, int out_size, void* d_ws, size_t ws_size,
                              hipStream_t stream) {
    const float* x = (const float*)d_in[0];
    float* out = (float*)d_out;
    dim3 grid(NN / SPAN, 16);
    feat_kernel<<<grid, 256, 0, stream>>>(x, out);
}